// Round 10
// baseline (73.760 us; speedup 1.0000x reference)
//
#include <hip/hip_runtime.h>
#include <stdint.h>

typedef __bf16 bf16x8 __attribute__((ext_vector_type(8)));
typedef float f32x4 __attribute__((ext_vector_type(4)));

#define N_ROWS 4096
#define KD 128
#define BM 64
#define NCHUNK 32
#define CHUNK 128                  // whole chunk staged once; ONE staging barrier
#define NBLOCKS (64 * NCHUNK)      // 2048 blocks = 64 I-tiles x 32 chunks

__device__ __forceinline__ unsigned short f32_to_bf16_rne(float f) {
    union { float f; uint32_t u; } v; v.f = f;
    uint32_t u = v.u;
    return (unsigned short)((u + 0x7FFFu + ((u >> 16) & 1u)) >> 16);
}

// XOR-swizzled LDS index for uint4 units: (row, kblock c) -> row*16 + (c ^ (row&15)).
// Coalesced ds_write_b128 and fragment ds_read_b128 both <=2-way per bank group
// (free, m136; validated R7: killed the 1.1M conflict cycles).
__device__ __forceinline__ int swz(int row, int c) { return row * 16 + (c ^ (row & 15)); }
__device__ __forceinline__ int swzL(int L) { return (L & ~15) | ((L & 15) ^ ((L >> 4) & 15)); }

// One wave per row: L2-normalize, round to bf16 (RNE), pack 2 elems/lane.
// Block 0 zeroes the fused kernel's control words (gsum,gcnt,gticket,sub x64).
__global__ __launch_bounds__(256) void normalize_kernel(const float* __restrict__ E,
                                                        unsigned short* __restrict__ out,
                                                        unsigned* __restrict__ ctrl) {
    if (blockIdx.x == 0 && threadIdx.x < 67) ctrl[threadIdx.x] = 0u;
    const int wave = threadIdx.x >> 6;
    const int lane = threadIdx.x & 63;
    const int row = blockIdx.x * 4 + wave;
    const float2 v = *(const float2*)&E[row * KD + lane * 2];
    float s = v.x * v.x + v.y * v.y;
#pragma unroll
    for (int m = 1; m < 64; m <<= 1) s += __shfl_xor(s, m, 64);
    float inv = 0.0f;
    if (s > 0.0f) {
        inv = rsqrtf(s);
        inv = inv * (1.5f - 0.5f * s * inv * inv);  // Newton step: ~1e-7 rel err
    }
    const unsigned short a = f32_to_bf16_rne(v.x * inv);
    const unsigned short b = f32_to_bf16_rne(v.y * inv);
    ((uint32_t*)out)[row * (KD / 2) + lane] = ((uint32_t)b << 16) | a;
}

// R9's proven one-barrier gram core (2048 blocks, 32 KB LDS -> 4 blocks/CU,
// 2 residency rounds) + fused finalize: agent-scope atomic partial stores,
// per-itile subticket (32 arrivals) -> group-last reduces its 64 rows,
// 2 atomicAdds + global ticket (64 arrivals) -> last block writes the loss.
// NO launch-bounds min-wave clamp (R8's regression: forced <=64 VGPR).
__global__ __launch_bounds__(256) void gram_kernel(const unsigned short* __restrict__ Ebits,
                                                   const int* __restrict__ labels,
                                                   unsigned long long* __restrict__ partials,
                                                   float* __restrict__ gsum,
                                                   unsigned* __restrict__ gcnt,
                                                   unsigned* __restrict__ gticket,
                                                   unsigned* __restrict__ subticket,
                                                   float* __restrict__ out) {
    __shared__ uint4 Bs4[CHUNK * (KD / 8)];  // 32 KB
    __shared__ int ljs[CHUNK];               // 512 B
    __shared__ unsigned s_old, g_old;
    __shared__ float ssum[4];
    __shared__ int scnt[4];

    const int tid = threadIdx.x;
    const int itile = blockIdx.x & 63;
    const int chunk = blockIdx.x >> 6;
    const int ibase = itile * BM;
    const int cbase = chunk * CHUNK;

    const int wave = tid >> 6, lane = tid & 63;
    const int quad = lane >> 4, l15 = lane & 15;
    const int igb = ibase + wave * 16 + quad * 4;  // row base for this lane's accs

    // Stage whole B-chunk: 8 coalesced uint4/thread -> swizzled LDS.
    {
        const uint4* src = (const uint4*)(Ebits + (size_t)cbase * KD);
#pragma unroll
        for (int it = 0; it < 8; ++it) {
            const int L = it * 256 + tid;
            Bs4[swzL(L)] = src[L];
        }
    }
    if (tid < CHUNK) ljs[tid] = labels[cbase + tid];

    // A fragments: one-time global gather, A[m=l15][k = s*32 + quad*8 ..+7].
    bf16x8 afrag[4];
    {
        const uint4* asrc = (const uint4*)Ebits;
        const int arow = ibase + wave * 16 + l15;
#pragma unroll
        for (int s = 0; s < 4; ++s) afrag[s] = *(const bf16x8*)&asrc[arow * 16 + s * 4 + quad];
    }
    int li_lab[4];
#pragma unroll
    for (int r = 0; r < 4; ++r) li_lab[r] = labels[igb + r];

    __syncthreads();  // the only staging barrier

    float minpos[4] = {2.0f, 2.0f, 2.0f, 2.0f};   // dots in [-1,1]; 2.0 = "no positive"
    float maxneg[4] = {-2.0f, -2.0f, -2.0f, -2.0f};

    // Pure ds_read + MFMA + epilogue stream: 8 j-tiles, no barriers.
#pragma unroll
    for (int t = 0; t < 8; ++t) {
        f32x4 acc = {0.f, 0.f, 0.f, 0.f};
#pragma unroll
        for (int s = 0; s < 4; ++s) {
            const bf16x8 bfrag = *(const bf16x8*)&Bs4[swz(t * 16 + l15, s * 4 + quad)];
            acc = __builtin_amdgcn_mfma_f32_16x16x32_bf16(afrag[s], bfrag, acc, 0, 0, 0);
        }
        // C/D layout: col = lane&15 (j), row = quad*4 + reg (i)  [m89/m91]
        const int jg = cbase + t * 16 + l15;
        const int lj = ljs[t * 16 + l15];
#pragma unroll
        for (int r = 0; r < 4; ++r) {
            const float d = acc[r];
            const bool same = (lj == li_lab[r]);
            const float dp = (same && (igb + r != jg)) ? d : 2.0f;
            const float dn = same ? -2.0f : d;
            minpos[r] = fminf(minpos[r], dp);
            maxneg[r] = fmaxf(maxneg[r], dn);
        }
    }

    // Reduce across the 16 col-lanes of each quad; rows live in (quad,reg).
#pragma unroll
    for (int m = 1; m < 16; m <<= 1) {
#pragma unroll
        for (int r = 0; r < 4; ++r) {
            minpos[r] = fminf(minpos[r], __shfl_xor(minpos[r], m, 64));
            maxneg[r] = fmaxf(maxneg[r], __shfl_xor(maxneg[r], m, 64));
        }
    }
    if (l15 == 0) {
#pragma unroll
        for (int r = 0; r < 4; ++r) {
            union { float2 f; unsigned long long u; } pv;
            pv.f = make_float2(minpos[r], maxneg[r]);
            // agent-scope atomic store -> coherence point (validated R8)
            __hip_atomic_store(&partials[(igb + r) * NCHUNK + chunk], pv.u,
                               __ATOMIC_RELAXED, __HIP_MEMORY_SCOPE_AGENT);
        }
    }

    // ---- per-itile ticket: 32 arrivals; group-last reduces its 64 rows ----
    __syncthreads();  // drains vmcnt(0): partial stores performed before ticket
    if (tid == 0) s_old = atomicAdd(&subticket[itile], 1u);
    __syncthreads();
    if (s_old == (unsigned)(NCHUNK - 1)) {
        const int rowl = tid >> 2, sub = tid & 3;   // 4 threads per row, 8 partials each
        const unsigned long long* pp = &partials[(ibase + rowl) * NCHUNK + sub * 8];
        float mp = 2.f, mn = -2.f;
#pragma unroll
        for (int k = 0; k < 8; ++k) {
            union { float2 f; unsigned long long u; } pv;
            pv.u = __hip_atomic_load(&pp[k], __ATOMIC_RELAXED, __HIP_MEMORY_SCOPE_AGENT);
            mp = fminf(mp, pv.f.x);
            mn = fmaxf(mn, pv.f.y);
        }
        mp = fminf(mp, __shfl_xor(mp, 1, 64)); mp = fminf(mp, __shfl_xor(mp, 2, 64));
        mn = fmaxf(mn, __shfl_xor(mn, 1, 64)); mn = fmaxf(mn, __shfl_xor(mn, 2, 64));
        float sum = 0.f; int cnt = 0;
        if (sub == 0 && mp < 1.5f && mn > -1.5f) {  // valid: >=1 pos and >=1 neg
            sum = fmaxf(0.f, mn - mp + 0.3f);       // relu(hp - hn + margin)
            cnt = 1;
        }
#pragma unroll
        for (int m = 1; m < 64; m <<= 1) {
            sum += __shfl_xor(sum, m, 64);
            cnt += __shfl_xor(cnt, m, 64);
        }
        if ((tid & 63) == 0) { ssum[tid >> 6] = sum; scnt[tid >> 6] = cnt; }
        __syncthreads();
        if (tid == 0) {
            atomicAdd(gsum, ssum[0] + ssum[1] + ssum[2] + ssum[3]);
            atomicAdd(gcnt, (unsigned)(scnt[0] + scnt[1] + scnt[2] + scnt[3]));
        }
        __syncthreads();  // drain the adds before the global ticket
        if (tid == 0) g_old = atomicAdd(gticket, 1u);
        __syncthreads();
        if (g_old == 63u && tid == 0) {
            const float S = __hip_atomic_load(gsum, __ATOMIC_RELAXED, __HIP_MEMORY_SCOPE_AGENT);
            const unsigned C = __hip_atomic_load(gcnt, __ATOMIC_RELAXED, __HIP_MEMORY_SCOPE_AGENT);
            out[0] = S / (float)(C > 0u ? C : 1u);
        }
    }
}

extern "C" void kernel_launch(void* const* d_in, const int* in_sizes, int n_in,
                              void* d_out, int out_size, void* d_ws, size_t ws_size,
                              hipStream_t stream) {
    const float* E = (const float*)d_in[0];
    const int* labels = (const int*)d_in[1];

    unsigned short* ebits = (unsigned short*)d_ws;                                    // 1 MiB
    unsigned long long* partials =
        (unsigned long long*)((char*)d_ws + (size_t)N_ROWS * KD * 2);                 // 1 MiB
    unsigned* ctrl = (unsigned*)(partials + N_ROWS * NCHUNK);  // [gsum][gcnt][gticket][sub x64]
    float* gsum = (float*)&ctrl[0];
    unsigned* gcnt = &ctrl[1];
    unsigned* gticket = &ctrl[2];
    unsigned* subticket = &ctrl[3];
    float* out = (float*)d_out;

    normalize_kernel<<<N_ROWS / 4, 256, 0, stream>>>(E, ebits, ctrl);
    gram_kernel<<<NBLOCKS, 256, 0, stream>>>(ebits, labels, partials, gsum, gcnt,
                                             gticket, subticket, out);
}

// Round 11
// 72.675 us; speedup vs baseline: 1.0149x; 1.0149x over previous
//
#include <hip/hip_runtime.h>
#include <stdint.h>

typedef __bf16 bf16x8 __attribute__((ext_vector_type(8)));
typedef float f32x4 __attribute__((ext_vector_type(4)));

#define N_ROWS 4096
#define KD 128
#define BM 64
#define NCHUNK 32
#define CHUNK 128                  // whole chunk staged once; ONE barrier per block
#define NBLOCKS (64 * NCHUNK)      // 2048 blocks = 64 I-tiles x 32 chunks; 2 rounds of 4/CU
#define FIN_BLOCKS 64

__device__ __forceinline__ unsigned short f32_to_bf16_rne(float f) {
    union { float f; uint32_t u; } v; v.f = f;
    uint32_t u = v.u;
    return (unsigned short)((u + 0x7FFFu + ((u >> 16) & 1u)) >> 16);
}

// XOR-swizzled LDS index for uint4 units: (row, kblock c) -> row*16 + (c ^ (row&15)).
// Coalesced ds_write_b128 and fragment ds_read_b128 both <=2-way per bank group
// (free, m136; validated R7: killed the 1.1M conflict cycles).
__device__ __forceinline__ int swz(int row, int c) { return row * 16 + (c ^ (row & 15)); }
__device__ __forceinline__ int swzL(int L) { return (L & ~15) | ((L & 15) ^ ((L >> 4) & 15)); }

// One wave per row: L2-normalize, round to bf16 (RNE), pack 2 elems/lane.
// Block 0 zeroes finalize's accumulators + ticket.
__global__ __launch_bounds__(256) void normalize_kernel(const float* __restrict__ E,
                                                        unsigned short* __restrict__ out,
                                                        unsigned* __restrict__ ctrl) {
    if (blockIdx.x == 0 && threadIdx.x < 3) ctrl[threadIdx.x] = 0u;
    const int wave = threadIdx.x >> 6;
    const int lane = threadIdx.x & 63;
    const int row = blockIdx.x * 4 + wave;
    const float2 v = *(const float2*)&E[row * KD + lane * 2];
    float s = v.x * v.x + v.y * v.y;
#pragma unroll
    for (int m = 1; m < 64; m <<= 1) s += __shfl_xor(s, m, 64);
    float inv = 0.0f;
    if (s > 0.0f) {
        inv = rsqrtf(s);
        inv = inv * (1.5f - 0.5f * s * inv * inv);  // Newton step: ~1e-7 rel err
    }
    const unsigned short a = f32_to_bf16_rne(v.x * inv);
    const unsigned short b = f32_to_bf16_rne(v.y * inv);
    ((uint32_t*)out)[row * (KD / 2) + lane] = ((uint32_t)b << 16) | a;
}

// 2048 blocks = 64 I-tiles x 32 chunks. Whole 128-row B-chunk staged to
// swizzled LDS once (32 KB -> 4 blocks/CU, 2 residency rounds for latency
// hiding); A-fragments global-gathered (no A LDS). Exactly ONE __syncthreads.
__global__ __launch_bounds__(256) void gram_kernel(const unsigned short* __restrict__ Ebits,
                                                   const int* __restrict__ labels,
                                                   float2* __restrict__ partials) {
    __shared__ uint4 Bs4[CHUNK * (KD / 8)];  // 32 KB
    __shared__ int ljs[CHUNK];               // 512 B

    const int tid = threadIdx.x;
    const int itile = blockIdx.x & 63;
    const int chunk = blockIdx.x >> 6;
    const int ibase = itile * BM;
    const int cbase = chunk * CHUNK;

    const int wave = tid >> 6, lane = tid & 63;
    const int quad = lane >> 4, l15 = lane & 15;
    const int igb = ibase + wave * 16 + quad * 4;  // row base for this lane's accs

    // Stage whole B-chunk: 8 coalesced uint4/thread -> swizzled LDS.
    {
        const uint4* src = (const uint4*)(Ebits + (size_t)cbase * KD);
#pragma unroll
        for (int it = 0; it < 8; ++it) {
            const int L = it * 256 + tid;
            Bs4[swzL(L)] = src[L];
        }
    }
    if (tid < CHUNK) ljs[tid] = labels[cbase + tid];

    // A fragments: one-time global gather, A[m=l15][k = s*32 + quad*8 ..+7].
    bf16x8 afrag[4];
    {
        const uint4* asrc = (const uint4*)Ebits;
        const int arow = ibase + wave * 16 + l15;
#pragma unroll
        for (int s = 0; s < 4; ++s) afrag[s] = *(const bf16x8*)&asrc[arow * 16 + s * 4 + quad];
    }
    int li_lab[4];
#pragma unroll
    for (int r = 0; r < 4; ++r) li_lab[r] = labels[igb + r];

    __syncthreads();  // the ONLY barrier

    float minpos[4] = {2.0f, 2.0f, 2.0f, 2.0f};   // dots in [-1,1]; 2.0 = "no positive"
    float maxneg[4] = {-2.0f, -2.0f, -2.0f, -2.0f};

    // Pure ds_read + MFMA + epilogue stream: 8 j-tiles, no barriers.
#pragma unroll
    for (int t = 0; t < 8; ++t) {
        f32x4 acc = {0.f, 0.f, 0.f, 0.f};
#pragma unroll
        for (int s = 0; s < 4; ++s) {
            const bf16x8 bfrag = *(const bf16x8*)&Bs4[swz(t * 16 + l15, s * 4 + quad)];
            acc = __builtin_amdgcn_mfma_f32_16x16x32_bf16(afrag[s], bfrag, acc, 0, 0, 0);
        }
        // C/D layout: col = lane&15 (j), row = quad*4 + reg (i)  [m89/m91]
        const int jg = cbase + t * 16 + l15;
        const int lj = ljs[t * 16 + l15];
#pragma unroll
        for (int r = 0; r < 4; ++r) {
            const float d = acc[r];
            const bool same = (lj == li_lab[r]);
            const float dp = (same && (igb + r != jg)) ? d : 2.0f;
            const float dn = same ? -2.0f : d;
            minpos[r] = fminf(minpos[r], dp);
            maxneg[r] = fmaxf(maxneg[r], dn);
        }
    }

    // Reduce across the 16 col-lanes of each quad; rows live in (quad,reg).
#pragma unroll
    for (int m = 1; m < 16; m <<= 1) {
#pragma unroll
        for (int r = 0; r < 4; ++r) {
            minpos[r] = fminf(minpos[r], __shfl_xor(minpos[r], m, 64));
            maxneg[r] = fmaxf(maxneg[r], __shfl_xor(maxneg[r], m, 64));
        }
    }
    if (l15 == 0) {
#pragma unroll
        for (int r = 0; r < 4; ++r)
            partials[(igb + r) * NCHUNK + chunk] = make_float2(minpos[r], maxneg[r]);
    }
}

// 64 blocks x 64 rows, 4 threads/row (each reads 4 float4 of the row's 32
// partials), shfl-combine, 2 atomicAdds + ticket; last block writes the loss.
__global__ __launch_bounds__(256) void finalize_kernel(const float2* __restrict__ partials,
                                                       float* __restrict__ gsum,
                                                       unsigned* __restrict__ gcnt,
                                                       unsigned* __restrict__ ticket,
                                                       float* __restrict__ out) {
    __shared__ float ssum[4];
    __shared__ int scnt[4];
    __shared__ unsigned s_old;

    const int tid = threadIdx.x;
    const int sub = tid & 3;
    const int row = blockIdx.x * 64 + (tid >> 2);

    const float4* p4 = (const float4*)&partials[row * NCHUNK];  // 16 float4 / row
    float mp = 2.f, mn = -2.f;
#pragma unroll
    for (int k = 0; k < 4; ++k) {
        const float4 v = p4[sub * 4 + k];      // {min,max,min,max}
        mp = fminf(mp, fminf(v.x, v.z));
        mn = fmaxf(mn, fmaxf(v.y, v.w));
    }
    mp = fminf(mp, __shfl_xor(mp, 1, 64)); mp = fminf(mp, __shfl_xor(mp, 2, 64));
    mn = fmaxf(mn, __shfl_xor(mn, 1, 64)); mn = fmaxf(mn, __shfl_xor(mn, 2, 64));

    float sum = 0.f; int cnt = 0;
    if (sub == 0 && mp < 1.5f && mn > -1.5f) {   // valid: >=1 pos and >=1 neg
        sum = fmaxf(0.f, mn - mp + 0.3f);        // relu(hp - hn + margin)
        cnt = 1;
    }
#pragma unroll
    for (int m = 1; m < 64; m <<= 1) {
        sum += __shfl_xor(sum, m, 64);
        cnt += __shfl_xor(cnt, m, 64);
    }
    const int wave = tid >> 6, lane = tid & 63;
    if (lane == 0) { ssum[wave] = sum; scnt[wave] = cnt; }
    __syncthreads();
    if (tid == 0) {
        atomicAdd(gsum, ssum[0] + ssum[1] + ssum[2] + ssum[3]);
        atomicAdd(gcnt, (unsigned)(scnt[0] + scnt[1] + scnt[2] + scnt[3]));
    }
    __syncthreads();                 // drain the adds (vmcnt) before ticket
    if (tid == 0) s_old = atomicAdd(ticket, 1u);
    __syncthreads();
    if (s_old == (unsigned)(FIN_BLOCKS - 1) && tid == 0) {
        const float S = __hip_atomic_load(gsum, __ATOMIC_RELAXED, __HIP_MEMORY_SCOPE_AGENT);
        const unsigned C = __hip_atomic_load(gcnt, __ATOMIC_RELAXED, __HIP_MEMORY_SCOPE_AGENT);
        out[0] = S / (float)(C > 0u ? C : 1u);
    }
}

extern "C" void kernel_launch(void* const* d_in, const int* in_sizes, int n_in,
                              void* d_out, int out_size, void* d_ws, size_t ws_size,
                              hipStream_t stream) {
    const float* E = (const float*)d_in[0];
    const int* labels = (const int*)d_in[1];

    unsigned short* ebits = (unsigned short*)d_ws;                          // 1 MiB
    float2* partials = (float2*)((char*)d_ws + (size_t)N_ROWS * KD * 2);    // 1 MiB
    unsigned* ctrl = (unsigned*)(partials + N_ROWS * NCHUNK);               // [gsum][gcnt][ticket]
    float* gsum = (float*)&ctrl[0];
    unsigned* gcnt = &ctrl[1];
    unsigned* ticket = &ctrl[2];
    float* out = (float*)d_out;

    normalize_kernel<<<N_ROWS / 4, 256, 0, stream>>>(E, ebits, ctrl);
    gram_kernel<<<NBLOCKS, 256, 0, stream>>>(ebits, labels, partials);
    finalize_kernel<<<FIN_BLOCKS, 256, 0, stream>>>(partials, gsum, gcnt, ticket, out);
}